// Round 8
// baseline (333.288 us; speedup 1.0000x reference)
//
#include <hip/hip_runtime.h>

#define N_NODES 100000
#define N_EDGES 1600000
#define IN_DIM 128
#define HID_DIM 128
#define OUT_DIM 64
#define BKT_SHIFT 8
#define BKT_SIZE 256
#define NBKT ((N_NODES + BKT_SIZE - 1) / BKT_SIZE)  // 391
#define B1 256                                       // blocks in hist/scatter passes
#define HIST_N (NBKT * B1)                           // 100096
#define HIST_N2 (2 * HIST_N)                         // 200192 (D then S)

typedef float v2f __attribute__((ext_vector_type(2)));
typedef float v4f __attribute__((ext_vector_type(4)));
typedef short v8s __attribute__((ext_vector_type(8)));

// ---------- helpers ----------
__device__ __forceinline__ unsigned int f2bf(float f) {  // fp32->bf16 RNE
  unsigned int u = __float_as_uint(f);
  return (u + 0x7FFFu + ((u >> 16) & 1u)) >> 16;
}

__device__ __forceinline__ void load4(const void* ei, int is64, int half, int base,
                                      int* v) {
  if (is64) {
    const long long* e = (const long long*)ei + (size_t)half * N_EDGES + base;
    longlong2 a = *(const longlong2*)e;
    longlong2 b = *(const longlong2*)(e + 2);
    v[0] = (int)a.x; v[1] = (int)a.y; v[2] = (int)b.x; v[3] = (int)b.y;
  } else {
    const int* e = (const int*)ei + (size_t)half * N_EDGES + base;
    int4 a = *(const int4*)e;
    v[0] = a.x; v[1] = a.y; v[2] = a.z; v[3] = a.w;
  }
}

// ---------- detect int64 vs int32 edge_index + zero S ----------
__global__ void detect_kernel(const unsigned int* ei, int* flag, float* S) {
  __shared__ int nz;
  if (threadIdx.x == 0) nz = 0;
  __syncthreads();
  unsigned int v = ei[1 + 2 * threadIdx.x];
  if (v != 0u) nz = 1;
  if (threadIdx.x < HID_DIM) S[threadIdx.x] = 0.f;
  __syncthreads();
  if (threadIdx.x == 0) *flag = (nz == 0) ? 1 : 0;
}

// ---------- pass A: per-block bucket histograms (dst then src, concatenated) ----
__global__ __launch_bounds__(256) void hist_kernel(const void* ei, const int* flag,
                                                   int* hist) {
  __shared__ int hd[NBKT], hs[NBKT];
  for (int k = threadIdx.x; k < NBKT; k += 256) { hd[k] = 0; hs[k] = 0; }
  __syncthreads();
  const int is64 = *flag;
  for (int g = blockIdx.x * 256 + threadIdx.x; g < N_EDGES / 4; g += B1 * 256) {
    int r[4], c[4];
    load4(ei, is64, 0, g * 4, r);
    load4(ei, is64, 1, g * 4, c);
#pragma unroll
    for (int k = 0; k < 4; k++) {
      atomicAdd(&hd[c[k] >> BKT_SHIFT], 1);
      atomicAdd(&hs[r[k] >> BKT_SHIFT], 1);
    }
  }
  __syncthreads();
  for (int k = threadIdx.x; k < NBKT; k += 256) {
    hist[k * B1 + blockIdx.x] = hd[k];
    hist[HIST_N + k * B1 + blockIdx.x] = hs[k];
  }
}

// ---------- exclusive scan over HIST_N2 (3 kernels, in place) ----------
__global__ void scan1_kernel(const int* cnt, int* part, int* bsum, int n) {
  __shared__ int tmp[256];
  int i = blockIdx.x * 256 + threadIdx.x;
  int v = (i < n) ? cnt[i] : 0;
  tmp[threadIdx.x] = v;
  __syncthreads();
  for (int off = 1; off < 256; off <<= 1) {
    int t2 = (threadIdx.x >= off) ? tmp[threadIdx.x - off] : 0;
    __syncthreads();
    tmp[threadIdx.x] += t2;
    __syncthreads();
  }
  if (i < n) part[i] = tmp[threadIdx.x] - v;  // exclusive within block
  if (threadIdx.x == 255) bsum[blockIdx.x] = tmp[255];
}

__global__ void scan2_kernel(int* bsum, int nb) {
  __shared__ int tmp[1024];
  int v = (threadIdx.x < nb) ? bsum[threadIdx.x] : 0;
  tmp[threadIdx.x] = v;
  __syncthreads();
  for (int off = 1; off < 1024; off <<= 1) {
    int t2 = (threadIdx.x >= off) ? tmp[threadIdx.x - off] : 0;
    __syncthreads();
    tmp[threadIdx.x] += t2;
    __syncthreads();
  }
  if (threadIdx.x < nb) bsum[threadIdx.x] = tmp[threadIdx.x] - v;  // exclusive
}

__global__ void scan3_kernel(int* arr, const int* bsum, int n) {
  int i = blockIdx.x * 256 + threadIdx.x;
  if (i < n) arr[i] += bsum[blockIdx.x];
}

// ---------- pass B: scatter packed pairs; D-partition [0,E), S-partition [E,2E) --
__global__ __launch_bounds__(256) void scatter_kernel(const void* ei, const int* flag,
                                                      const int* hist,
                                                      unsigned int* pairs) {
  __shared__ int cd[NBKT], cs[NBKT];
  for (int k = threadIdx.x; k < NBKT; k += 256) {
    cd[k] = hist[k * B1 + blockIdx.x];
    cs[k] = hist[HIST_N + k * B1 + blockIdx.x];
  }
  __syncthreads();
  const int is64 = *flag;
  for (int g = blockIdx.x * 256 + threadIdx.x; g < N_EDGES / 4; g += B1 * 256) {
    int r[4], c[4];
    load4(ei, is64, 0, g * 4, r);
    load4(ei, is64, 1, g * 4, c);
#pragma unroll
    for (int k = 0; k < 4; k++) {
      int pd = atomicAdd(&cd[c[k] >> BKT_SHIFT], 1);
      pairs[pd] = ((unsigned int)(c[k] & (BKT_SIZE - 1)) << 17) | (unsigned int)r[k];
      int ps = atomicAdd(&cs[r[k] >> BKT_SHIFT], 1);
      pairs[ps] = ((unsigned int)(r[k] & (BKT_SIZE - 1)) << 17) | (unsigned int)c[k];
    }
  }
}

// ---------- pass C: per-bucket exact CSR + rowptr + dinv ----------
__global__ __launch_bounds__(256) void csr_kernel(const int* hist,
                                                  const unsigned int* pairs,
                                                  int* rowptr, int* csr, float* dinv) {
  __shared__ int cnt[BKT_SIZE], sc[BKT_SIZE], cur[BKT_SIZE];
  const int k = blockIdx.x;
  const int base = hist[k * B1];
  const int end = (k == NBKT - 1) ? N_EDGES : hist[(k + 1) * B1];
  const int nseg = end - base;
  const int l = threadIdx.x;
  cnt[l] = 0;
  __syncthreads();
  for (int i = l; i < nseg; i += 256) atomicAdd(&cnt[pairs[base + i] >> 17], 1);
  __syncthreads();
  sc[l] = cnt[l];
  __syncthreads();
  for (int off = 1; off < BKT_SIZE; off <<= 1) {
    int v = (l >= off) ? sc[l - off] : 0;
    __syncthreads();
    sc[l] += v;
    __syncthreads();
  }
  {
    int excl = sc[l] - cnt[l];
    cur[l] = base + excl;
    int v = k * BKT_SIZE + l;
    if (v < N_NODES) {
      rowptr[v] = base + excl;
      dinv[v] = rsqrtf((float)(cnt[l] + 1));
    }
  }
  if (k == NBKT - 1 && l == 0) rowptr[N_NODES] = N_EDGES;
  __syncthreads();
  for (int i = l; i < nseg; i += 256) {
    unsigned int pk = pairs[base + i];
    int pos = atomicAdd(&cur[pk >> 17], 1);
    csr[pos] = (int)(pk & 0x1FFFFu);
  }
}

// ---------- pass C2: per-src-bucket wacc = sum of dinv[dst] over out-edges ------
__global__ __launch_bounds__(256) void outsum_kernel(const int* hist,
                                                     const unsigned int* pairs,
                                                     const float* __restrict__ dinv,
                                                     float* wacc) {
  __shared__ float fb[BKT_SIZE];
  const int k = blockIdx.x;
  const int base = hist[HIST_N + k * B1];
  const int end = (k == NBKT - 1) ? 2 * N_EDGES : hist[HIST_N + (k + 1) * B1];
  fb[threadIdx.x] = 0.f;
  __syncthreads();
  for (int i = base + threadIdx.x; i < end; i += 256) {
    unsigned int pk = pairs[i];
    atomicAdd(&fb[pk >> 17], dinv[pk & 0x1FFFFu]);
  }
  __syncthreads();
  int v = k * BKT_SIZE + threadIdx.x;
  if (v < N_NODES) wacc[v] = fb[threadIdx.x];
}

// ---------- G(fp8) = dinv ⊙ (x @ W1), bf16 MFMA ----------
// 128 rows/block; LDS: x-tile [128][136] bf16 + W^T [128][136] bf16 (padded rows).
__global__ __launch_bounds__(256) void gemm_kernel(const float* __restrict__ x,
                                                   const float* __restrict__ W,
                                                   const float* __restrict__ dinv,
                                                   unsigned int* __restrict__ G) {
  __shared__ __align__(16) unsigned short lx[128][136];
  __shared__ __align__(16) unsigned short lwt[128][136];
  const int t = threadIdx.x;
  const int row0 = blockIdx.x * 128;

  // stage W^T (bf16): W[k][c] -> lwt[c][k]
  {
    const float4* W4 = (const float4*)W;
    for (int it = 0; it < 16; ++it) {
      int idx = t + 256 * it;          // over 4096 float4: k*32 + c4
      int k = idx >> 5, c4 = (idx & 31) * 4;
      float4 w = W4[idx];
      lwt[c4 + 0][k] = (unsigned short)f2bf(w.x);
      lwt[c4 + 1][k] = (unsigned short)f2bf(w.y);
      lwt[c4 + 2][k] = (unsigned short)f2bf(w.z);
      lwt[c4 + 3][k] = (unsigned short)f2bf(w.w);
    }
  }
  // stage x tile (bf16, row-major)
  {
    const float4* x4 = (const float4*)(x + (size_t)row0 * IN_DIM);
    for (int it = 0; it < 16; ++it) {
      int idx = t + 256 * it;          // r*32 + kq4
      int r = idx >> 5, kq = (idx & 31) * 4;
      float4 v = make_float4(0.f, 0.f, 0.f, 0.f);
      if (row0 + r < N_NODES) v = x4[idx];
      unsigned int p0 = (f2bf(v.y) << 16) | f2bf(v.x);
      unsigned int p1 = (f2bf(v.w) << 16) | f2bf(v.z);
      *(uint2*)&lx[r][kq] = make_uint2(p0, p1);
    }
  }
  __syncthreads();

  const int lane = t & 63;
  const int wv = t >> 6;          // 0..3
  const int m0 = wv * 32;         // this wave's 32 rows
  const int lrow = lane & 15;
  const int lk = (lane >> 4) * 8; // k-offset within 32-chunk

  v4f acc[2][8];
#pragma unroll
  for (int si = 0; si < 2; si++)
#pragma unroll
    for (int n = 0; n < 8; n++) acc[si][n] = (v4f){0.f, 0.f, 0.f, 0.f};

#pragma unroll
  for (int kk = 0; kk < 128; kk += 32) {
    v8s a0 = *(const v8s*)&lx[m0 + lrow][kk + lk];
    v8s a1 = *(const v8s*)&lx[m0 + 16 + lrow][kk + lk];
#pragma unroll
    for (int n = 0; n < 8; n++) {
      v8s b = *(const v8s*)&lwt[n * 16 + lrow][kk + lk];
      acc[0][n] = __builtin_amdgcn_mfma_f32_16x16x32_bf16(a0, b, acc[0][n], 0, 0, 0);
      acc[1][n] = __builtin_amdgcn_mfma_f32_16x16x32_bf16(a1, b, acc[1][n], 0, 0, 0);
    }
  }

  // epilogue: C/D layout col=lane&15, row=(lane>>4)*4+i
  unsigned char* G8 = (unsigned char*)G;
  float dv[2][4];
#pragma unroll
  for (int si = 0; si < 2; si++)
#pragma unroll
    for (int i = 0; i < 4; i++) {
      int r = row0 + m0 + si * 16 + (lane >> 4) * 4 + i;
      dv[si][i] = (r < N_NODES) ? dinv[r] : 0.f;
    }
#pragma unroll
  for (int si = 0; si < 2; si++)
#pragma unroll
    for (int n = 0; n < 8; n++) {
      int colg = n * 16 + (lane & 15);
#pragma unroll
      for (int i = 0; i < 4; i++) {
        int r = row0 + m0 + si * 16 + (lane >> 4) * 4 + i;
        if (r < N_NODES) {
          float v = acc[si][n][i] * dv[si][i];
          int pk = __builtin_amdgcn_cvt_pk_fp8_f32(v, v, 0, false);
          G8[(size_t)r * HID_DIM + colg] = (unsigned char)(pk & 0xFF);
        }
      }
    }
}

// ---------- aggregate: column-sliced, XCD-affine gather (fp8 G) ----------
// slice = blockIdx&3 (round-robin XCDs -> 1 slice per XCD, 3.2 MB L2-resident).
// Lane layout: grp=lane>>3 covers edge subgroup, dwo=lane&7 covers 4 cols.
__global__ __launch_bounds__(256) void aggregate_kernel(
    const unsigned int* __restrict__ G, const int* __restrict__ rowptr,
    const int* __restrict__ csr, const float* __restrict__ dinv,
    const float* __restrict__ wacc, const float* __restrict__ b1,
    float* __restrict__ S) {
  const int lane = threadIdx.x & 63;
  const int grp = lane >> 3;
  const int dwo = lane & 7;
  const int slice = blockIdx.x & 3;
  const int sbase = slice * 8;  // dword offset within 32-dword row
  const int wid = (blockIdx.x >> 2) * 4 + (threadIdx.x >> 6);
  const int nw = (gridDim.x >> 2) * 4;
  const float4 b = ((const float4*)b1)[sbase + dwo];
  v2f s01 = {0.f, 0.f}, s23 = {0.f, 0.f};

  for (int c = wid; c < N_NODES; c += nw) {
    const int start = rowptr[c];
    const int cnum = rowptr[c + 1] - start;
    v2f a01 = {0.f, 0.f}, a23 = {0.f, 0.f};
    if (grp == 0) {  // self loop
      unsigned int g = G[c * 32 + sbase + dwo];
      a01 = __builtin_amdgcn_cvt_pk_f32_fp8((int)g, false);
      a23 = __builtin_amdgcn_cvt_pk_f32_fp8((int)g, true);
    }
    for (int j0 = 0; j0 < cnum; j0 += 64) {
      int src = 0;
      if (j0 + lane < cnum)
        src = __builtin_nontemporal_load(&csr[start + j0 + lane]);
      const int m = min(64, cnum - j0);
      int i = 0;
      for (; i + 16 <= m; i += 16) {
        int s0 = __shfl(src, i + grp);
        int s1 = __shfl(src, i + 8 + grp);
        unsigned int g0 = G[s0 * 32 + sbase + dwo];
        unsigned int g1 = G[s1 * 32 + sbase + dwo];
        a01 += __builtin_amdgcn_cvt_pk_f32_fp8((int)g0, false) +
               __builtin_amdgcn_cvt_pk_f32_fp8((int)g1, false);
        a23 += __builtin_amdgcn_cvt_pk_f32_fp8((int)g0, true) +
               __builtin_amdgcn_cvt_pk_f32_fp8((int)g1, true);
      }
      for (; i < m; i += 8) {
        int e = i + grp;
        int s = __shfl(src, min(e, m - 1));  // all lanes active in shfl
        if (e < m) {
          unsigned int g = G[s * 32 + sbase + dwo];
          a01 += __builtin_amdgcn_cvt_pk_f32_fp8((int)g, false);
          a23 += __builtin_amdgcn_cvt_pk_f32_fp8((int)g, true);
        }
      }
    }
    // merge the 8 edge-subgroups (butterfly over lane bits 3,4,5)
#pragma unroll
    for (int off = 8; off < 64; off <<= 1) {
      a01.x += __shfl_xor(a01.x, off);
      a01.y += __shfl_xor(a01.y, off);
      a23.x += __shfl_xor(a23.x, off);
      a23.y += __shfl_xor(a23.y, off);
    }
    if (grp == 0) {
      float d = dinv[c];
      float wc = d * (wacc[c] + d);  // layer-2 weight
      s01.x += wc * fmaxf(fmaf(d, a01.x, b.x), 0.f);
      s01.y += wc * fmaxf(fmaf(d, a01.y, b.y), 0.f);
      s23.x += wc * fmaxf(fmaf(d, a23.x, b.z), 0.f);
      s23.y += wc * fmaxf(fmaf(d, a23.y, b.w), 0.f);
    }
  }

  __shared__ float ls[32];
  if (threadIdx.x < 32) ls[threadIdx.x] = 0.f;
  __syncthreads();
  if (grp == 0) {
    atomicAdd(&ls[dwo * 4 + 0], s01.x);
    atomicAdd(&ls[dwo * 4 + 1], s01.y);
    atomicAdd(&ls[dwo * 4 + 2], s23.x);
    atomicAdd(&ls[dwo * 4 + 3], s23.y);
  }
  __syncthreads();
  if (threadIdx.x < 32) atomicAdd(&S[slice * 32 + threadIdx.x], ls[threadIdx.x]);
}

// ---------- out[j] = (1/N) * S @ W2 + b2 ----------
__global__ void finish_kernel(const float* __restrict__ S, const float* __restrict__ W2,
                              const float* __restrict__ b2, float* __restrict__ out) {
  int j = threadIdx.x;  // 64
  float acc = 0.f;
  for (int k = 0; k < HID_DIM; k++) acc += S[k] * W2[k * OUT_DIM + j];
  out[j] = acc * (1.0f / N_NODES) + b2[j];
}

extern "C" void kernel_launch(void* const* d_in, const int* in_sizes, int n_in,
                              void* d_out, int out_size, void* d_ws, size_t ws_size,
                              hipStream_t stream) {
  const float* x  = (const float*)d_in[0];
  const void*  ei = d_in[1];
  const float* W1 = (const float*)d_in[2];
  const float* b1 = (const float*)d_in[3];
  const float* W2 = (const float*)d_in[4];
  const float* b2 = (const float*)d_in[5];
  float* out = (float*)d_out;

  char* p = (char*)d_ws;
  size_t off = 0;
  auto alloc = [&](size_t bytes) -> void* {
    void* r = p + off;
    off = (off + bytes + 63) & ~(size_t)63;
    return r;
  };
  int*   flag   = (int*)alloc(64);
  int*   hist   = (int*)alloc((size_t)HIST_N2 * 4);                // 800 KB
  int*   bsum   = (int*)alloc(1024 * 4);
  unsigned int* pairs = (unsigned int*)alloc((size_t)2 * N_EDGES * 4);  // 12.8 MB
  int*   rowptr = (int*)alloc(((size_t)N_NODES + 1) * 4);
  int*   csr    = (int*)alloc((size_t)N_EDGES * 4);                // 6.4 MB
  float* dinv   = (float*)alloc((size_t)N_NODES * 4);
  float* wacc   = (float*)alloc((size_t)N_NODES * 4);
  float* S      = (float*)alloc(HID_DIM * 4);
  unsigned int* G = (unsigned int*)alloc((size_t)N_NODES * HID_DIM);  // 12.8 MB fp8
  (void)ws_size; (void)n_in; (void)in_sizes; (void)out_size;

  const int NBH = HIST_N2 / 256;  // 782, exact

  detect_kernel<<<1, 256, 0, stream>>>((const unsigned int*)ei, flag, S);
  hist_kernel<<<B1, 256, 0, stream>>>(ei, flag, hist);
  scan1_kernel<<<NBH, 256, 0, stream>>>(hist, hist, bsum, HIST_N2);
  scan2_kernel<<<1, 1024, 0, stream>>>(bsum, NBH);
  scan3_kernel<<<NBH, 256, 0, stream>>>(hist, bsum, HIST_N2);
  scatter_kernel<<<B1, 256, 0, stream>>>(ei, flag, hist, pairs);
  csr_kernel<<<NBKT, 256, 0, stream>>>(hist, pairs, rowptr, csr, dinv);
  outsum_kernel<<<NBKT, 256, 0, stream>>>(hist, pairs, dinv, wacc);
  gemm_kernel<<<(N_NODES + 127) / 128, 256, 0, stream>>>(x, W1, dinv, G);
  aggregate_kernel<<<2048, 256, 0, stream>>>(G, rowptr, csr, dinv, wacc, b1, S);
  finish_kernel<<<1, 64, 0, stream>>>(S, W2, b2, out);
}

// Round 9
// 298.409 us; speedup vs baseline: 1.1169x; 1.1169x over previous
//
#include <hip/hip_runtime.h>

#define N_NODES 100000
#define N_EDGES 1600000
#define IN_DIM 128
#define HID_DIM 128
#define OUT_DIM 64
#define BKT_SHIFT 8
#define BKT_SIZE 256
#define NBKT ((N_NODES + BKT_SIZE - 1) / BKT_SIZE)  // 391
#define B1 256                                       // hist/scatter blocks
#define HIST_N (NBKT * B1)                           // 100096
#define HIST_N2 (2 * HIST_N)                         // 200192
#define GEMM_BLKS ((N_NODES + 127) / 128)            // 782

typedef float v2f __attribute__((ext_vector_type(2)));
typedef float v4f __attribute__((ext_vector_type(4)));
typedef short v8s __attribute__((ext_vector_type(8)));

// ---------- helpers ----------
__device__ __forceinline__ unsigned int f2bf(float f) {  // fp32->bf16 RNE
  unsigned int u = __float_as_uint(f);
  return (u + 0x7FFFu + ((u >> 16) & 1u)) >> 16;
}

__device__ __forceinline__ void load4(const void* ei, int is64, int half, int base,
                                      int* v) {
  if (is64) {
    const long long* e = (const long long*)ei + (size_t)half * N_EDGES + base;
    longlong2 a = *(const longlong2*)e;
    longlong2 b = *(const longlong2*)(e + 2);
    v[0] = (int)a.x; v[1] = (int)a.y; v[2] = (int)b.x; v[3] = (int)b.y;
  } else {
    const int* e = (const int*)ei + (size_t)half * N_EDGES + base;
    int4 a = *(const int4*)e;
    v[0] = a.x; v[1] = a.y; v[2] = a.z; v[3] = a.w;
  }
}

// block-local int64 detection: odd dwords of first 256 int64 entries all zero
__device__ __forceinline__ int detect64_block(const unsigned int* ei, int* sh) {
  if (threadIdx.x == 0) *sh = 0;
  __syncthreads();
  if (ei[1 + 2 * threadIdx.x] != 0u) *sh = 1;
  __syncthreads();
  return (*sh == 0) ? 1 : 0;
}

// ---------- front kernel: blocks [0,782) = raw GEMM; [782,1038) = hist ----------
__global__ __launch_bounds__(256) void front_kernel(const float* __restrict__ x,
                                                    const float* __restrict__ W,
                                                    const void* ei,
                                                    unsigned int* __restrict__ G,
                                                    int* hist, float* S) {
  __shared__ __align__(16) char smem[2 * 128 * 136 * 2];  // 69632 B
  if (blockIdx.x >= GEMM_BLKS) {
    // ---- hist role ----
    int* hd = (int*)smem;
    int* hs = hd + NBKT;
    int* sh = hs + NBKT;
    const int hb = blockIdx.x - GEMM_BLKS;
    if (hb == 0 && threadIdx.x < HID_DIM) S[threadIdx.x] = 0.f;
    const int is64 = detect64_block((const unsigned int*)ei, sh);
    for (int k = threadIdx.x; k < NBKT; k += 256) { hd[k] = 0; hs[k] = 0; }
    __syncthreads();
    for (int g = hb * 256 + threadIdx.x; g < N_EDGES / 4; g += B1 * 256) {
      int r[4], c[4];
      load4(ei, is64, 0, g * 4, r);
      load4(ei, is64, 1, g * 4, c);
#pragma unroll
      for (int k = 0; k < 4; k++) {
        atomicAdd(&hd[c[k] >> BKT_SHIFT], 1);
        atomicAdd(&hs[r[k] >> BKT_SHIFT], 1);
      }
    }
    __syncthreads();
    for (int k = threadIdx.x; k < NBKT; k += 256) {
      hist[k * B1 + hb] = hd[k];
      hist[HIST_N + k * B1 + hb] = hs[k];
    }
    return;
  }
  // ---- gemm role: G_raw(fp8) = x @ W1, bf16 MFMA ----
  typedef unsigned short us_row[136];
  us_row* lx = (us_row*)smem;
  us_row* lwt = (us_row*)(smem + 128 * 136 * 2);
  const int t = threadIdx.x;
  const int row0 = blockIdx.x * 128;

  {  // stage W^T bf16
    const float4* W4 = (const float4*)W;
    for (int it = 0; it < 16; ++it) {
      int idx = t + 256 * it;  // k*32 + c4
      int k = idx >> 5, c4 = (idx & 31) * 4;
      float4 w = W4[idx];
      lwt[c4 + 0][k] = (unsigned short)f2bf(w.x);
      lwt[c4 + 1][k] = (unsigned short)f2bf(w.y);
      lwt[c4 + 2][k] = (unsigned short)f2bf(w.z);
      lwt[c4 + 3][k] = (unsigned short)f2bf(w.w);
    }
  }
  {  // stage x tile bf16
    const float4* x4 = (const float4*)(x + (size_t)row0 * IN_DIM);
    for (int it = 0; it < 16; ++it) {
      int idx = t + 256 * it;  // r*32 + kq4
      int r = idx >> 5, kq = (idx & 31) * 4;
      float4 v = make_float4(0.f, 0.f, 0.f, 0.f);
      if (row0 + r < N_NODES) v = x4[idx];
      unsigned int p0 = (f2bf(v.y) << 16) | f2bf(v.x);
      unsigned int p1 = (f2bf(v.w) << 16) | f2bf(v.z);
      *(uint2*)&lx[r][kq] = make_uint2(p0, p1);
    }
  }
  __syncthreads();

  const int lane = t & 63;
  const int wv = t >> 6;
  const int m0 = wv * 32;
  const int lrow = lane & 15;
  const int lk = (lane >> 4) * 8;

  v4f acc[2][8];
#pragma unroll
  for (int si = 0; si < 2; si++)
#pragma unroll
    for (int n = 0; n < 8; n++) acc[si][n] = (v4f){0.f, 0.f, 0.f, 0.f};

#pragma unroll
  for (int kk = 0; kk < 128; kk += 32) {
    v8s a0 = *(const v8s*)&lx[m0 + lrow][kk + lk];
    v8s a1 = *(const v8s*)&lx[m0 + 16 + lrow][kk + lk];
#pragma unroll
    for (int n = 0; n < 8; n++) {
      v8s b = *(const v8s*)&lwt[n * 16 + lrow][kk + lk];
      acc[0][n] = __builtin_amdgcn_mfma_f32_16x16x32_bf16(a0, b, acc[0][n], 0, 0, 0);
      acc[1][n] = __builtin_amdgcn_mfma_f32_16x16x32_bf16(a1, b, acc[1][n], 0, 0, 0);
    }
  }

  unsigned char* G8 = (unsigned char*)G;
#pragma unroll
  for (int si = 0; si < 2; si++)
#pragma unroll
    for (int n = 0; n < 8; n++) {
      int colg = n * 16 + (lane & 15);
#pragma unroll
      for (int i = 0; i < 4; i++) {
        int r = row0 + m0 + si * 16 + (lane >> 4) * 4 + i;
        if (r < N_NODES) {
          float v = acc[si][n][i];
          int pk = __builtin_amdgcn_cvt_pk_fp8_f32(v, v, 0, false);
          G8[(size_t)r * HID_DIM + colg] = (unsigned char)(pk & 0xFF);
        }
      }
    }
}

// ---------- scan1: per-block exclusive partials + block sums ----------
__global__ void scan1_kernel(int* arr, int* bsum, int n) {
  __shared__ int tmp[256];
  int i = blockIdx.x * 256 + threadIdx.x;
  int v = (i < n) ? arr[i] : 0;
  tmp[threadIdx.x] = v;
  __syncthreads();
  for (int off = 1; off < 256; off <<= 1) {
    int t2 = (threadIdx.x >= off) ? tmp[threadIdx.x - off] : 0;
    __syncthreads();
    tmp[threadIdx.x] += t2;
    __syncthreads();
  }
  if (i < n) arr[i] = tmp[threadIdx.x] - v;  // exclusive within block
  if (threadIdx.x == 255) bsum[blockIdx.x] = tmp[255];
}

// ---------- scan2: exclusive scan of 782 block sums ----------
__global__ void scan2_kernel(int* bsum, int nb) {
  __shared__ int tmp[1024];
  int v = (threadIdx.x < nb) ? bsum[threadIdx.x] : 0;
  tmp[threadIdx.x] = v;
  __syncthreads();
  for (int off = 1; off < 1024; off <<= 1) {
    int t2 = (threadIdx.x >= off) ? tmp[threadIdx.x - off] : 0;
    __syncthreads();
    tmp[threadIdx.x] += t2;
    __syncthreads();
  }
  if (threadIdx.x < nb) bsum[threadIdx.x] = tmp[threadIdx.x] - v;
}

// ---------- scatter: pairs into (bucket) partitions; bsum folded in ----------
__global__ __launch_bounds__(256) void scatter_kernel(const void* ei, const int* hist,
                                                      const int* bsum,
                                                      unsigned int* pairs) {
  __shared__ int cd[NBKT], cs[NBKT], sh[1];
  const int is64 = detect64_block((const unsigned int*)ei, sh);
  for (int k = threadIdx.x; k < NBKT; k += 256) {
    cd[k] = hist[k * B1 + blockIdx.x] + bsum[k];
    cs[k] = hist[HIST_N + k * B1 + blockIdx.x] + bsum[NBKT + k];
  }
  __syncthreads();
  for (int g = blockIdx.x * 256 + threadIdx.x; g < N_EDGES / 4; g += B1 * 256) {
    int r[4], c[4];
    load4(ei, is64, 0, g * 4, r);
    load4(ei, is64, 1, g * 4, c);
#pragma unroll
    for (int k = 0; k < 4; k++) {
      int pd = atomicAdd(&cd[c[k] >> BKT_SHIFT], 1);
      pairs[pd] = ((unsigned int)(c[k] & (BKT_SIZE - 1)) << 17) | (unsigned int)r[k];
      int ps = atomicAdd(&cs[r[k] >> BKT_SHIFT], 1);
      pairs[ps] = ((unsigned int)(r[k] & (BKT_SIZE - 1)) << 17) | (unsigned int)c[k];
    }
  }
}

// ---------- csr: per-bucket exact CSR + rowptr + dinv ----------
__global__ __launch_bounds__(256) void csr_kernel(const int* hist, const int* bsum,
                                                  const unsigned int* pairs,
                                                  int* rowptr, int* csr, float* dinv) {
  __shared__ int cnt[BKT_SIZE], sc[BKT_SIZE], cur[BKT_SIZE];
  const int k = blockIdx.x;
  const int base = hist[k * B1] + bsum[k];
  const int end = (k == NBKT - 1) ? N_EDGES : hist[(k + 1) * B1] + bsum[k + 1];
  const int nseg = end - base;
  const int l = threadIdx.x;
  cnt[l] = 0;
  __syncthreads();
  for (int i = l; i < nseg; i += 256) atomicAdd(&cnt[pairs[base + i] >> 17], 1);
  __syncthreads();
  sc[l] = cnt[l];
  __syncthreads();
  for (int off = 1; off < BKT_SIZE; off <<= 1) {
    int v = (l >= off) ? sc[l - off] : 0;
    __syncthreads();
    sc[l] += v;
    __syncthreads();
  }
  {
    int excl = sc[l] - cnt[l];
    cur[l] = base + excl;
    int v = k * BKT_SIZE + l;
    if (v < N_NODES) {
      rowptr[v] = base + excl;
      dinv[v] = rsqrtf((float)(cnt[l] + 1));
    }
  }
  if (k == NBKT - 1 && l == 0) rowptr[N_NODES] = N_EDGES;
  __syncthreads();
  for (int i = l; i < nseg; i += 256) {
    unsigned int pk = pairs[base + i];
    int pos = atomicAdd(&cur[pk >> 17], 1);
    csr[pos] = (int)(pk & 0x1FFFFu);
  }
}

// ---------- outsum: wacc[r] = sum of dinv[dst] over out-edges ----------
__global__ __launch_bounds__(256) void outsum_kernel(const int* hist, const int* bsum,
                                                     const unsigned int* pairs,
                                                     const float* __restrict__ dinv,
                                                     float* wacc) {
  __shared__ float fb[BKT_SIZE];
  const int k = blockIdx.x;
  const int base = hist[HIST_N + k * B1] + bsum[NBKT + k];
  const int end =
      (k == NBKT - 1) ? 2 * N_EDGES : hist[HIST_N + (k + 1) * B1] + bsum[NBKT + k + 1];
  fb[threadIdx.x] = 0.f;
  __syncthreads();
  for (int i = base + threadIdx.x; i < end; i += 256) {
    unsigned int pk = pairs[i];
    atomicAdd(&fb[pk >> 17], dinv[pk & 0x1FFFFu]);
  }
  __syncthreads();
  int v = k * BKT_SIZE + threadIdx.x;
  if (v < N_NODES) wacc[v] = fb[threadIdx.x];
}

// ---------- aggregate: gather raw fp8 G, scale by dinv[src], 2 edges/wave ----------
__global__ __launch_bounds__(256) void aggregate_kernel(
    const unsigned int* __restrict__ G, const int* __restrict__ rowptr,
    const int* __restrict__ csr, const float* __restrict__ dinv,
    const float* __restrict__ wacc, const float* __restrict__ b1,
    float* __restrict__ S) {
  const int lane = threadIdx.x & 63;
  const int sub = lane & 31;   // col group: cols [4*sub, 4*sub+4)
  const int half = lane >> 5;  // edge parity
  const int wid = blockIdx.x * (blockDim.x >> 6) + (threadIdx.x >> 6);
  const int nwaves = gridDim.x * (blockDim.x >> 6);
  const float4 b = ((const float4*)b1)[sub];
  v2f s01 = {0.f, 0.f}, s23 = {0.f, 0.f};

  for (int c = wid; c < N_NODES; c += nwaves) {
    const int start = rowptr[c];
    const int cnum = rowptr[c + 1] - start;
    float d = 0.f;
    v2f a01 = {0.f, 0.f}, a23 = {0.f, 0.f};
    if (half == 0) {  // self loop, scaled by dinv[c]
      d = dinv[c];
      unsigned int g = G[c * 32 + sub];
      a01 = __builtin_amdgcn_cvt_pk_f32_fp8((int)g, false) * d;
      a23 = __builtin_amdgcn_cvt_pk_f32_fp8((int)g, true) * d;
    }
    for (int j0 = 0; j0 < cnum; j0 += 64) {
      int src = 0;
      float dvl = 0.f;
      if (j0 + lane < cnum) {
        src = __builtin_nontemporal_load(&csr[start + j0 + lane]);
        dvl = dinv[src];
      }
      const int m = min(64, cnum - j0);
      int i = 0;
      for (; i + 16 <= m; i += 16) {  // 8 edges per half, 8 loads in flight
        int s0 = __shfl(src, i + half);
        int s1 = __shfl(src, i + 2 + half);
        int s2 = __shfl(src, i + 4 + half);
        int s3 = __shfl(src, i + 6 + half);
        int s4 = __shfl(src, i + 8 + half);
        int s5 = __shfl(src, i + 10 + half);
        int s6 = __shfl(src, i + 12 + half);
        int s7 = __shfl(src, i + 14 + half);
        float w0 = __shfl(dvl, i + half);
        float w1 = __shfl(dvl, i + 2 + half);
        float w2 = __shfl(dvl, i + 4 + half);
        float w3 = __shfl(dvl, i + 6 + half);
        float w4 = __shfl(dvl, i + 8 + half);
        float w5 = __shfl(dvl, i + 10 + half);
        float w6 = __shfl(dvl, i + 12 + half);
        float w7 = __shfl(dvl, i + 14 + half);
        unsigned int g0 = G[s0 * 32 + sub];
        unsigned int g1 = G[s1 * 32 + sub];
        unsigned int g2 = G[s2 * 32 + sub];
        unsigned int g3 = G[s3 * 32 + sub];
        unsigned int g4 = G[s4 * 32 + sub];
        unsigned int g5 = G[s5 * 32 + sub];
        unsigned int g6 = G[s6 * 32 + sub];
        unsigned int g7 = G[s7 * 32 + sub];
        a01 += __builtin_amdgcn_cvt_pk_f32_fp8((int)g0, false) * w0;
        a23 += __builtin_amdgcn_cvt_pk_f32_fp8((int)g0, true) * w0;
        a01 += __builtin_amdgcn_cvt_pk_f32_fp8((int)g1, false) * w1;
        a23 += __builtin_amdgcn_cvt_pk_f32_fp8((int)g1, true) * w1;
        a01 += __builtin_amdgcn_cvt_pk_f32_fp8((int)g2, false) * w2;
        a23 += __builtin_amdgcn_cvt_pk_f32_fp8((int)g2, true) * w2;
        a01 += __builtin_amdgcn_cvt_pk_f32_fp8((int)g3, false) * w3;
        a23 += __builtin_amdgcn_cvt_pk_f32_fp8((int)g3, true) * w3;
        a01 += __builtin_amdgcn_cvt_pk_f32_fp8((int)g4, false) * w4;
        a23 += __builtin_amdgcn_cvt_pk_f32_fp8((int)g4, true) * w4;
        a01 += __builtin_amdgcn_cvt_pk_f32_fp8((int)g5, false) * w5;
        a23 += __builtin_amdgcn_cvt_pk_f32_fp8((int)g5, true) * w5;
        a01 += __builtin_amdgcn_cvt_pk_f32_fp8((int)g6, false) * w6;
        a23 += __builtin_amdgcn_cvt_pk_f32_fp8((int)g6, true) * w6;
        a01 += __builtin_amdgcn_cvt_pk_f32_fp8((int)g7, false) * w7;
        a23 += __builtin_amdgcn_cvt_pk_f32_fp8((int)g7, true) * w7;
      }
      for (; i + 2 <= m; i += 2) {
        int s = __shfl(src, i + half);
        float w = __shfl(dvl, i + half);
        unsigned int g = G[s * 32 + sub];
        a01 += __builtin_amdgcn_cvt_pk_f32_fp8((int)g, false) * w;
        a23 += __builtin_amdgcn_cvt_pk_f32_fp8((int)g, true) * w;
      }
      if (i < m) {  // odd leftover: lanes of half 0 only
        int s = __shfl(src, i);
        float w = __shfl(dvl, i);
        if (half == 0) {
          unsigned int g = G[s * 32 + sub];
          a01 += __builtin_amdgcn_cvt_pk_f32_fp8((int)g, false) * w;
          a23 += __builtin_amdgcn_cvt_pk_f32_fp8((int)g, true) * w;
        }
      }
    }
    // merge upper half into lower
    a01.x += __shfl(a01.x, sub + 32);
    a01.y += __shfl(a01.y, sub + 32);
    a23.x += __shfl(a23.x, sub + 32);
    a23.y += __shfl(a23.y, sub + 32);
    if (half == 0) {
      float wc = d * (wacc[c] + d);  // layer-2 weight
      s01.x += wc * fmaxf(fmaf(d, a01.x, b.x), 0.f);
      s01.y += wc * fmaxf(fmaf(d, a01.y, b.y), 0.f);
      s23.x += wc * fmaxf(fmaf(d, a23.x, b.z), 0.f);
      s23.y += wc * fmaxf(fmaf(d, a23.y, b.w), 0.f);
    }
  }

  __shared__ float ls[HID_DIM];
  if (threadIdx.x < HID_DIM) ls[threadIdx.x] = 0.f;
  __syncthreads();
  if (half == 0) {
    atomicAdd(&ls[4 * sub + 0], s01.x);
    atomicAdd(&ls[4 * sub + 1], s01.y);
    atomicAdd(&ls[4 * sub + 2], s23.x);
    atomicAdd(&ls[4 * sub + 3], s23.y);
  }
  __syncthreads();
  if (threadIdx.x < HID_DIM) atomicAdd(&S[threadIdx.x], ls[threadIdx.x]);
}

// ---------- out[j] = (1/N) * S @ W2 + b2 ----------
__global__ void finish_kernel(const float* __restrict__ S, const float* __restrict__ W2,
                              const float* __restrict__ b2, float* __restrict__ out) {
  int j = threadIdx.x;  // 64
  float acc = 0.f;
  for (int k = 0; k < HID_DIM; k++) acc += S[k] * W2[k * OUT_DIM + j];
  out[j] = acc * (1.0f / N_NODES) + b2[j];
}

extern "C" void kernel_launch(void* const* d_in, const int* in_sizes, int n_in,
                              void* d_out, int out_size, void* d_ws, size_t ws_size,
                              hipStream_t stream) {
  const float* x  = (const float*)d_in[0];
  const void*  ei = d_in[1];
  const float* W1 = (const float*)d_in[2];
  const float* b1 = (const float*)d_in[3];
  const float* W2 = (const float*)d_in[4];
  const float* b2 = (const float*)d_in[5];
  float* out = (float*)d_out;

  char* p = (char*)d_ws;
  size_t off = 0;
  auto alloc = [&](size_t bytes) -> void* {
    void* r = p + off;
    off = (off + bytes + 63) & ~(size_t)63;
    return r;
  };
  int*   hist   = (int*)alloc((size_t)HIST_N2 * 4);                // 800 KB
  int*   bsum   = (int*)alloc(1024 * 4);
  unsigned int* pairs = (unsigned int*)alloc((size_t)2 * N_EDGES * 4);  // 12.8 MB
  int*   rowptr = (int*)alloc(((size_t)N_NODES + 1) * 4);
  int*   csr    = (int*)alloc((size_t)N_EDGES * 4);                // 6.4 MB
  float* dinv   = (float*)alloc((size_t)N_NODES * 4);
  float* wacc   = (float*)alloc((size_t)N_NODES * 4);
  float* S      = (float*)alloc(HID_DIM * 4);
  unsigned int* G = (unsigned int*)alloc((size_t)N_NODES * HID_DIM);  // 12.8 MB fp8
  (void)ws_size; (void)n_in; (void)in_sizes; (void)out_size;

  const int NBH = HIST_N2 / 256;  // 782, exact

  front_kernel<<<GEMM_BLKS + B1, 256, 0, stream>>>(x, W1, ei, G, hist, S);
  scan1_kernel<<<NBH, 256, 0, stream>>>(hist, bsum, HIST_N2);
  scan2_kernel<<<1, 1024, 0, stream>>>(bsum, NBH);
  scatter_kernel<<<B1, 256, 0, stream>>>(ei, hist, bsum, pairs);
  csr_kernel<<<NBKT, 256, 0, stream>>>(hist, bsum, pairs, rowptr, csr, dinv);
  outsum_kernel<<<NBKT, 256, 0, stream>>>(hist, bsum, pairs, dinv, wacc);
  aggregate_kernel<<<2048, 256, 0, stream>>>(G, rowptr, csr, dinv, wacc, b1, S);
  finish_kernel<<<1, 64, 0, stream>>>(S, W2, b2, out);
}

// Round 10
// 290.747 us; speedup vs baseline: 1.1463x; 1.0264x over previous
//
#include <hip/hip_runtime.h>

#define N_NODES 100000
#define N_EDGES 1600000
#define IN_DIM 128
#define HID_DIM 128
#define OUT_DIM 64
#define BKT_SHIFT 8
#define BKT_SIZE 256
#define NBKT ((N_NODES + BKT_SIZE - 1) / BKT_SIZE)  // 391
#define B1 256                                       // hist/scatter blocks
#define HIST_N (NBKT * B1)                           // 100096
#define HIST_N2 (2 * HIST_N)                         // 200192
#define GEMM_BLKS ((N_NODES + 127) / 128)            // 782

typedef float v2f __attribute__((ext_vector_type(2)));
typedef float v4f __attribute__((ext_vector_type(4)));
typedef short v8s __attribute__((ext_vector_type(8)));

// ---------- helpers ----------
__device__ __forceinline__ unsigned int f2bf(float f) {  // fp32->bf16 RNE
  unsigned int u = __float_as_uint(f);
  return (u + 0x7FFFu + ((u >> 16) & 1u)) >> 16;
}

__device__ __forceinline__ void load4(const void* ei, int is64, int half, int base,
                                      int* v) {
  if (is64) {
    const long long* e = (const long long*)ei + (size_t)half * N_EDGES + base;
    longlong2 a = *(const longlong2*)e;
    longlong2 b = *(const longlong2*)(e + 2);
    v[0] = (int)a.x; v[1] = (int)a.y; v[2] = (int)b.x; v[3] = (int)b.y;
  } else {
    const int* e = (const int*)ei + (size_t)half * N_EDGES + base;
    int4 a = *(const int4*)e;
    v[0] = a.x; v[1] = a.y; v[2] = a.z; v[3] = a.w;
  }
}

// block-local int64 detection: odd dwords of first 256 int64 entries all zero
__device__ __forceinline__ int detect64_block(const unsigned int* ei, int* sh) {
  if (threadIdx.x == 0) *sh = 0;
  __syncthreads();
  if (ei[1 + 2 * threadIdx.x] != 0u) *sh = 1;
  __syncthreads();
  return (*sh == 0) ? 1 : 0;
}

// ---------- front kernel: blocks [0,782) = raw GEMM; [782,1038) = hist ----------
__global__ __launch_bounds__(256) void front_kernel(const float* __restrict__ x,
                                                    const float* __restrict__ W,
                                                    const void* ei,
                                                    unsigned int* __restrict__ G,
                                                    int* hist, float* S) {
  __shared__ __align__(16) char smem[2 * 128 * 136 * 2];  // 69632 B
  if (blockIdx.x >= GEMM_BLKS) {
    // ---- hist role ----
    int* hd = (int*)smem;
    int* hs = hd + NBKT;
    int* sh = hs + NBKT;
    const int hb = blockIdx.x - GEMM_BLKS;
    if (hb == 0 && threadIdx.x < HID_DIM) S[threadIdx.x] = 0.f;
    const int is64 = detect64_block((const unsigned int*)ei, sh);
    for (int k = threadIdx.x; k < NBKT; k += 256) { hd[k] = 0; hs[k] = 0; }
    __syncthreads();
    for (int g = hb * 256 + threadIdx.x; g < N_EDGES / 4; g += B1 * 256) {
      int r[4], c[4];
      load4(ei, is64, 0, g * 4, r);
      load4(ei, is64, 1, g * 4, c);
#pragma unroll
      for (int k = 0; k < 4; k++) {
        atomicAdd(&hd[c[k] >> BKT_SHIFT], 1);
        atomicAdd(&hs[r[k] >> BKT_SHIFT], 1);
      }
    }
    __syncthreads();
    for (int k = threadIdx.x; k < NBKT; k += 256) {
      hist[k * B1 + hb] = hd[k];
      hist[HIST_N + k * B1 + hb] = hs[k];
    }
    return;
  }
  // ---- gemm role: G_raw(fp8) = x @ W1, bf16 MFMA ----
  typedef unsigned short us_row[136];
  us_row* lx = (us_row*)smem;
  us_row* lwt = (us_row*)(smem + 128 * 136 * 2);
  const int t = threadIdx.x;
  const int row0 = blockIdx.x * 128;

  {  // stage W^T bf16
    const float4* W4 = (const float4*)W;
    for (int it = 0; it < 16; ++it) {
      int idx = t + 256 * it;  // k*32 + c4
      int k = idx >> 5, c4 = (idx & 31) * 4;
      float4 w = W4[idx];
      lwt[c4 + 0][k] = (unsigned short)f2bf(w.x);
      lwt[c4 + 1][k] = (unsigned short)f2bf(w.y);
      lwt[c4 + 2][k] = (unsigned short)f2bf(w.z);
      lwt[c4 + 3][k] = (unsigned short)f2bf(w.w);
    }
  }
  {  // stage x tile bf16
    const float4* x4 = (const float4*)(x + (size_t)row0 * IN_DIM);
    for (int it = 0; it < 16; ++it) {
      int idx = t + 256 * it;  // r*32 + kq4
      int r = idx >> 5, kq = (idx & 31) * 4;
      float4 v = make_float4(0.f, 0.f, 0.f, 0.f);
      if (row0 + r < N_NODES) v = x4[idx];
      unsigned int p0 = (f2bf(v.y) << 16) | f2bf(v.x);
      unsigned int p1 = (f2bf(v.w) << 16) | f2bf(v.z);
      *(uint2*)&lx[r][kq] = make_uint2(p0, p1);
    }
  }
  __syncthreads();

  const int lane = t & 63;
  const int wv = t >> 6;
  const int m0 = wv * 32;
  const int lrow = lane & 15;
  const int lk = (lane >> 4) * 8;

  v4f acc[2][8];
#pragma unroll
  for (int si = 0; si < 2; si++)
#pragma unroll
    for (int n = 0; n < 8; n++) acc[si][n] = (v4f){0.f, 0.f, 0.f, 0.f};

#pragma unroll
  for (int kk = 0; kk < 128; kk += 32) {
    v8s a0 = *(const v8s*)&lx[m0 + lrow][kk + lk];
    v8s a1 = *(const v8s*)&lx[m0 + 16 + lrow][kk + lk];
#pragma unroll
    for (int n = 0; n < 8; n++) {
      v8s b = *(const v8s*)&lwt[n * 16 + lrow][kk + lk];
      acc[0][n] = __builtin_amdgcn_mfma_f32_16x16x32_bf16(a0, b, acc[0][n], 0, 0, 0);
      acc[1][n] = __builtin_amdgcn_mfma_f32_16x16x32_bf16(a1, b, acc[1][n], 0, 0, 0);
    }
  }

  unsigned char* G8 = (unsigned char*)G;
#pragma unroll
  for (int si = 0; si < 2; si++)
#pragma unroll
    for (int n = 0; n < 8; n++) {
      int colg = n * 16 + (lane & 15);
#pragma unroll
      for (int i = 0; i < 4; i++) {
        int r = row0 + m0 + si * 16 + (lane >> 4) * 4 + i;
        if (r < N_NODES) {
          float v = acc[si][n][i];
          int pk = __builtin_amdgcn_cvt_pk_fp8_f32(v, v, 0, false);
          G8[(size_t)r * HID_DIM + colg] = (unsigned char)(pk & 0xFF);
        }
      }
    }
}

// ---------- scan1: per-block exclusive partials + block sums ----------
__global__ void scan1_kernel(int* arr, int* bsum, int n) {
  __shared__ int tmp[256];
  int i = blockIdx.x * 256 + threadIdx.x;
  int v = (i < n) ? arr[i] : 0;
  tmp[threadIdx.x] = v;
  __syncthreads();
  for (int off = 1; off < 256; off <<= 1) {
    int t2 = (threadIdx.x >= off) ? tmp[threadIdx.x - off] : 0;
    __syncthreads();
    tmp[threadIdx.x] += t2;
    __syncthreads();
  }
  if (i < n) arr[i] = tmp[threadIdx.x] - v;  // exclusive within block
  if (threadIdx.x == 255) bsum[blockIdx.x] = tmp[255];
}

// ---------- scan2: exclusive scan of 782 block sums ----------
__global__ void scan2_kernel(int* bsum, int nb) {
  __shared__ int tmp[1024];
  int v = (threadIdx.x < nb) ? bsum[threadIdx.x] : 0;
  tmp[threadIdx.x] = v;
  __syncthreads();
  for (int off = 1; off < 1024; off <<= 1) {
    int t2 = (threadIdx.x >= off) ? tmp[threadIdx.x - off] : 0;
    __syncthreads();
    tmp[threadIdx.x] += t2;
    __syncthreads();
  }
  if (threadIdx.x < nb) bsum[threadIdx.x] = tmp[threadIdx.x] - v;
}

// ---------- scatter: pairs into (bucket) partitions; bsum folded in ----------
__global__ __launch_bounds__(256) void scatter_kernel(const void* ei, const int* hist,
                                                      const int* bsum,
                                                      unsigned int* pairs) {
  __shared__ int cd[NBKT], cs[NBKT], sh[1];
  const int is64 = detect64_block((const unsigned int*)ei, sh);
  for (int k = threadIdx.x; k < NBKT; k += 256) {
    cd[k] = hist[k * B1 + blockIdx.x] + bsum[k];
    cs[k] = hist[HIST_N + k * B1 + blockIdx.x] + bsum[NBKT + k];
  }
  __syncthreads();
  for (int g = blockIdx.x * 256 + threadIdx.x; g < N_EDGES / 4; g += B1 * 256) {
    int r[4], c[4];
    load4(ei, is64, 0, g * 4, r);
    load4(ei, is64, 1, g * 4, c);
#pragma unroll
    for (int k = 0; k < 4; k++) {
      int pd = atomicAdd(&cd[c[k] >> BKT_SHIFT], 1);
      pairs[pd] = ((unsigned int)(c[k] & (BKT_SIZE - 1)) << 17) | (unsigned int)r[k];
      int ps = atomicAdd(&cs[r[k] >> BKT_SHIFT], 1);
      pairs[ps] = ((unsigned int)(r[k] & (BKT_SIZE - 1)) << 17) | (unsigned int)c[k];
    }
  }
}

// ---------- csr: per-bucket exact CSR + rowptr + dinv ----------
__global__ __launch_bounds__(256) void csr_kernel(const int* hist, const int* bsum,
                                                  const unsigned int* pairs,
                                                  int* rowptr, int* csr, float* dinv) {
  __shared__ int cnt[BKT_SIZE], sc[BKT_SIZE], cur[BKT_SIZE];
  const int k = blockIdx.x;
  const int base = hist[k * B1] + bsum[k];
  const int end = (k == NBKT - 1) ? N_EDGES : hist[(k + 1) * B1] + bsum[k + 1];
  const int nseg = end - base;
  const int l = threadIdx.x;
  cnt[l] = 0;
  __syncthreads();
  for (int i = l; i < nseg; i += 256) atomicAdd(&cnt[pairs[base + i] >> 17], 1);
  __syncthreads();
  sc[l] = cnt[l];
  __syncthreads();
  for (int off = 1; off < BKT_SIZE; off <<= 1) {
    int v = (l >= off) ? sc[l - off] : 0;
    __syncthreads();
    sc[l] += v;
    __syncthreads();
  }
  {
    int excl = sc[l] - cnt[l];
    cur[l] = base + excl;
    int v = k * BKT_SIZE + l;
    if (v < N_NODES) {
      rowptr[v] = base + excl;
      dinv[v] = rsqrtf((float)(cnt[l] + 1));
    }
  }
  if (k == NBKT - 1 && l == 0) rowptr[N_NODES] = N_EDGES;
  __syncthreads();
  for (int i = l; i < nseg; i += 256) {
    unsigned int pk = pairs[base + i];
    int pos = atomicAdd(&cur[pk >> 17], 1);
    csr[pos] = (int)(pk & 0x1FFFFu);
  }
}

// ---------- outsum + G prescale: wacc[r] = sum dinv[dst]; G[r] *= dinv[r] --------
__global__ __launch_bounds__(256) void outsum_kernel(const int* hist, const int* bsum,
                                                     const unsigned int* pairs,
                                                     const float* __restrict__ dinv,
                                                     float* wacc,
                                                     unsigned int* __restrict__ G) {
  __shared__ float fb[BKT_SIZE];
  const int k = blockIdx.x;
  const int base = hist[HIST_N + k * B1] + bsum[NBKT + k];
  const int end =
      (k == NBKT - 1) ? 2 * N_EDGES : hist[HIST_N + (k + 1) * B1] + bsum[NBKT + k + 1];
  fb[threadIdx.x] = 0.f;
  __syncthreads();
  for (int i = base + threadIdx.x; i < end; i += 256) {
    unsigned int pk = pairs[i];
    atomicAdd(&fb[pk >> 17], dinv[pk & 0x1FFFFu]);
  }
  // ---- G prescale for this bucket's 256 rows (coalesced; runs concurrently) ----
  {
    const int j0 = k * BKT_SIZE * 32;  // first dword of bucket
#pragma unroll
    for (int it = 0; it < 32; ++it) {
      int j = j0 + it * 256 + threadIdx.x;
      int node = j >> 5;
      if (node < N_NODES) {
        float d = dinv[node];
        unsigned int g = G[j];
        v2f lo = __builtin_amdgcn_cvt_pk_f32_fp8((int)g, false) * d;
        v2f hi = __builtin_amdgcn_cvt_pk_f32_fp8((int)g, true) * d;
        int pk2 = __builtin_amdgcn_cvt_pk_fp8_f32(lo.x, lo.y, 0, false);
        pk2 = __builtin_amdgcn_cvt_pk_fp8_f32(hi.x, hi.y, pk2, true);
        G[j] = (unsigned int)pk2;
      }
    }
  }
  __syncthreads();
  int v = k * BKT_SIZE + threadIdx.x;
  if (v < N_NODES) wacc[v] = fb[threadIdx.x];
}

// ---------- aggregate: round-7 proven form (prescaled fp8 G, 2 edges/wave) -------
__global__ __launch_bounds__(256) void aggregate_kernel(
    const unsigned int* __restrict__ G, const int* __restrict__ rowptr,
    const int* __restrict__ csr, const float* __restrict__ dinv,
    const float* __restrict__ wacc, const float* __restrict__ b1,
    float* __restrict__ S) {
  const int lane = threadIdx.x & 63;
  const int sub = lane & 31;   // col group: cols [4*sub, 4*sub+4)
  const int half = lane >> 5;  // edge parity
  const int wid = blockIdx.x * (blockDim.x >> 6) + (threadIdx.x >> 6);
  const int nwaves = gridDim.x * (blockDim.x >> 6);
  const float4 b = ((const float4*)b1)[sub];
  v2f s01 = {0.f, 0.f}, s23 = {0.f, 0.f};

  for (int c = wid; c < N_NODES; c += nwaves) {
    const int start = rowptr[c];
    const int cnum = rowptr[c + 1] - start;
    v2f a01 = {0.f, 0.f}, a23 = {0.f, 0.f};
    if (half == 0) {  // self loop (G prescaled)
      unsigned int g = G[c * 32 + sub];
      a01 = __builtin_amdgcn_cvt_pk_f32_fp8((int)g, false);
      a23 = __builtin_amdgcn_cvt_pk_f32_fp8((int)g, true);
    }
    for (int j0 = 0; j0 < cnum; j0 += 64) {
      int src = 0;
      if (j0 + lane < cnum)
        src = __builtin_nontemporal_load(&csr[start + j0 + lane]);
      const int m = min(64, cnum - j0);
      int i = 0;
      for (; i + 8 <= m; i += 8) {
        int s0 = __shfl(src, i + half);
        int s1 = __shfl(src, i + 2 + half);
        int s2 = __shfl(src, i + 4 + half);
        int s3 = __shfl(src, i + 6 + half);
        unsigned int g0 = G[s0 * 32 + sub];
        unsigned int g1 = G[s1 * 32 + sub];
        unsigned int g2 = G[s2 * 32 + sub];
        unsigned int g3 = G[s3 * 32 + sub];
        a01 += __builtin_amdgcn_cvt_pk_f32_fp8((int)g0, false) +
               __builtin_amdgcn_cvt_pk_f32_fp8((int)g1, false);
        a23 += __builtin_amdgcn_cvt_pk_f32_fp8((int)g0, true) +
               __builtin_amdgcn_cvt_pk_f32_fp8((int)g1, true);
        a01 += __builtin_amdgcn_cvt_pk_f32_fp8((int)g2, false) +
               __builtin_amdgcn_cvt_pk_f32_fp8((int)g3, false);
        a23 += __builtin_amdgcn_cvt_pk_f32_fp8((int)g2, true) +
               __builtin_amdgcn_cvt_pk_f32_fp8((int)g3, true);
      }
      for (; i + 2 <= m; i += 2) {
        int s = __shfl(src, i + half);
        unsigned int g = G[s * 32 + sub];
        a01 += __builtin_amdgcn_cvt_pk_f32_fp8((int)g, false);
        a23 += __builtin_amdgcn_cvt_pk_f32_fp8((int)g, true);
      }
      if (i < m) {  // odd leftover: half-0 lanes only
        int s = __shfl(src, i);
        if (half == 0) {
          unsigned int g = G[s * 32 + sub];
          a01 += __builtin_amdgcn_cvt_pk_f32_fp8((int)g, false);
          a23 += __builtin_amdgcn_cvt_pk_f32_fp8((int)g, true);
        }
      }
    }
    // merge upper half into lower
    a01.x += __shfl(a01.x, sub + 32);
    a01.y += __shfl(a01.y, sub + 32);
    a23.x += __shfl(a23.x, sub + 32);
    a23.y += __shfl(a23.y, sub + 32);
    if (half == 0) {
      float d = dinv[c];
      float wc = d * (wacc[c] + d);  // layer-2 weight
      s01.x += wc * fmaxf(fmaf(d, a01.x, b.x), 0.f);
      s01.y += wc * fmaxf(fmaf(d, a01.y, b.y), 0.f);
      s23.x += wc * fmaxf(fmaf(d, a23.x, b.z), 0.f);
      s23.y += wc * fmaxf(fmaf(d, a23.y, b.w), 0.f);
    }
  }

  __shared__ float ls[HID_DIM];
  if (threadIdx.x < HID_DIM) ls[threadIdx.x] = 0.f;
  __syncthreads();
  if (half == 0) {
    atomicAdd(&ls[4 * sub + 0], s01.x);
    atomicAdd(&ls[4 * sub + 1], s01.y);
    atomicAdd(&ls[4 * sub + 2], s23.x);
    atomicAdd(&ls[4 * sub + 3], s23.y);
  }
  __syncthreads();
  if (threadIdx.x < HID_DIM) atomicAdd(&S[threadIdx.x], ls[threadIdx.x]);
}

// ---------- out[j] = (1/N) * S @ W2 + b2 ----------
__global__ void finish_kernel(const float* __restrict__ S, const float* __restrict__ W2,
                              const float* __restrict__ b2, float* __restrict__ out) {
  int j = threadIdx.x;  // 64
  float acc = 0.f;
  for (int k = 0; k < HID_DIM; k++) acc += S[k] * W2[k * OUT_DIM + j];
  out[j] = acc * (1.0f / N_NODES) + b2[j];
}

extern "C" void kernel_launch(void* const* d_in, const int* in_sizes, int n_in,
                              void* d_out, int out_size, void* d_ws, size_t ws_size,
                              hipStream_t stream) {
  const float* x  = (const float*)d_in[0];
  const void*  ei = d_in[1];
  const float* W1 = (const float*)d_in[2];
  const float* b1 = (const float*)d_in[3];
  const float* W2 = (const float*)d_in[4];
  const float* b2 = (const float*)d_in[5];
  float* out = (float*)d_out;

  char* p = (char*)d_ws;
  size_t off = 0;
  auto alloc = [&](size_t bytes) -> void* {
    void* r = p + off;
    off = (off + bytes + 63) & ~(size_t)63;
    return r;
  };
  int*   hist   = (int*)alloc((size_t)HIST_N2 * 4);                // 800 KB
  int*   bsum   = (int*)alloc(1024 * 4);
  unsigned int* pairs = (unsigned int*)alloc((size_t)2 * N_EDGES * 4);  // 12.8 MB
  int*   rowptr = (int*)alloc(((size_t)N_NODES + 1) * 4);
  int*   csr    = (int*)alloc((size_t)N_EDGES * 4);                // 6.4 MB
  float* dinv   = (float*)alloc((size_t)N_NODES * 4);
  float* wacc   = (float*)alloc((size_t)N_NODES * 4);
  float* S      = (float*)alloc(HID_DIM * 4);
  unsigned int* G = (unsigned int*)alloc((size_t)N_NODES * HID_DIM);  // 12.8 MB fp8
  (void)ws_size; (void)n_in; (void)in_sizes; (void)out_size;

  const int NBH = HIST_N2 / 256;  // 782, exact

  front_kernel<<<GEMM_BLKS + B1, 256, 0, stream>>>(x, W1, ei, G, hist, S);
  scan1_kernel<<<NBH, 256, 0, stream>>>(hist, bsum, HIST_N2);
  scan2_kernel<<<1, 1024, 0, stream>>>(bsum, NBH);
  scatter_kernel<<<B1, 256, 0, stream>>>(ei, hist, bsum, pairs);
  csr_kernel<<<NBKT, 256, 0, stream>>>(hist, bsum, pairs, rowptr, csr, dinv);
  outsum_kernel<<<NBKT, 256, 0, stream>>>(hist, bsum, pairs, dinv, wacc, G);
  aggregate_kernel<<<2048, 256, 0, stream>>>(G, rowptr, csr, dinv, wacc, b1, S);
  finish_kernel<<<1, 64, 0, stream>>>(S, W2, b2, out);
}